// Round 1
// baseline (4833.873 us; speedup 1.0000x reference)
//
#include <hip/hip_runtime.h>

#define E_N 262144
#define T_N 1048576

#define LSTR 132      // padded row stride (floats) for LDS x-tiles: breaks bank conflicts, keeps 16B align (132*4=528=33*16)
#define TILE_E 64
#define NTHR 512

__device__ __forceinline__ float silu_f(float x) {
  return x / (1.0f + __expf(-x));
}

// load rows [r0, r0+64) of Wg[*][ncols] into lw (contiguous 64*ncols floats)
__device__ __forceinline__ void load_w_rows(const float* __restrict__ Wg, float* __restrict__ lw,
                                            int r0, int ncols) {
  const float4* src = (const float4*)(Wg + (size_t)r0 * ncols);
  float4* dst = (float4*)lw;
  int n4 = 64 * ncols / 4;
  for (int i = threadIdx.x; i < n4; i += NTHR) dst[i] = src[i];
}

// global tile (TILE_E x ncols, row stride ncols) -> lds tile (row stride LSTR)
__device__ __forceinline__ void load_x_tile(const float* __restrict__ g, float* __restrict__ lx, int ncols) {
  int n4 = TILE_E * ncols / 4;
  int c4s = ncols / 4;
  for (int i = threadIdx.x; i < n4; i += NTHR) {
    int r = i / c4s, c = (i % c4s) * 4;
    *(float4*)(lx + r * LSTR + c) = *(const float4*)(g + (size_t)r * ncols + c);
  }
}

// acc[2][8] = lx[e0..e0+1][0..K) @ Wg[K][128] + bias
// mapping: j0 = (tid&15)*8, e0 = (tid>>4)*2
__device__ __forceinline__ void mm_n128(const float* __restrict__ lx, const float* __restrict__ Wg,
                                        const float* __restrict__ bias, float* __restrict__ lw,
                                        float acc[2][8], int K, int e0, int j0) {
#pragma unroll
  for (int a = 0; a < 2; ++a)
#pragma unroll
    for (int c = 0; c < 8; ++c) acc[a][c] = 0.0f;
  for (int h = 0; h < K; h += 64) {
    __syncthreads();                 // previous users of lw / lx writers done
    load_w_rows(Wg, lw, h, 128);
    __syncthreads();
    const float* xa = lx + e0 * LSTR + h;
    const float* xb = xa + LSTR;
#pragma unroll 8
    for (int kk = 0; kk < 64; ++kk) {
      float4 w0 = *(const float4*)(lw + kk * 128 + j0);
      float4 w1 = *(const float4*)(lw + kk * 128 + j0 + 4);
      float va = xa[kk], vb = xb[kk];
      acc[0][0] += va * w0.x; acc[0][1] += va * w0.y; acc[0][2] += va * w0.z; acc[0][3] += va * w0.w;
      acc[0][4] += va * w1.x; acc[0][5] += va * w1.y; acc[0][6] += va * w1.z; acc[0][7] += va * w1.w;
      acc[1][0] += vb * w0.x; acc[1][1] += vb * w0.y; acc[1][2] += vb * w0.z; acc[1][3] += vb * w0.w;
      acc[1][4] += vb * w1.x; acc[1][5] += vb * w1.y; acc[1][6] += vb * w1.z; acc[1][7] += vb * w1.w;
    }
  }
  float4 b0 = *(const float4*)(bias + j0);
  float4 b1 = *(const float4*)(bias + j0 + 4);
#pragma unroll
  for (int a = 0; a < 2; ++a) {
    acc[a][0] += b0.x; acc[a][1] += b0.y; acc[a][2] += b0.z; acc[a][3] += b0.w;
    acc[a][4] += b1.x; acc[a][5] += b1.y; acc[a][6] += b1.z; acc[a][7] += b1.w;
  }
}

// acc[8] = lx[e][0..128) @ Wg[128][64] + bias ; mapping: j0 = (tid&7)*8, e = tid>>3
__device__ __forceinline__ void mm_n64(const float* __restrict__ lx, const float* __restrict__ Wg,
                                       const float* __restrict__ bias, float* __restrict__ lw,
                                       float acc[8], int e, int j0) {
#pragma unroll
  for (int c = 0; c < 8; ++c) acc[c] = 0.0f;
  for (int h = 0; h < 128; h += 64) {
    __syncthreads();
    load_w_rows(Wg, lw, h, 64);
    __syncthreads();
    const float* xp = lx + e * LSTR + h;
#pragma unroll 8
    for (int kk = 0; kk < 64; ++kk) {
      float4 w0 = *(const float4*)(lw + kk * 64 + j0);
      float4 w1 = *(const float4*)(lw + kk * 64 + j0 + 4);
      float v = xp[kk];
      acc[0] += v * w0.x; acc[1] += v * w0.y; acc[2] += v * w0.z; acc[3] += v * w0.w;
      acc[4] += v * w1.x; acc[5] += v * w1.y; acc[6] += v * w1.z; acc[7] += v * w1.w;
    }
  }
  float4 b0 = *(const float4*)(bias + j0);
  float4 b1 = *(const float4*)(bias + j0 + 4);
  acc[0] += b0.x; acc[1] += b0.y; acc[2] += b0.z; acc[3] += b0.w;
  acc[4] += b1.x; acc[5] += b1.y; acc[6] += b1.z; acc[7] += b1.w;
}

__device__ __forceinline__ void store_tile(float* __restrict__ dst, const float v[2][8], int e0, int j0) {
#pragma unroll
  for (int a = 0; a < 2; ++a) {
    *(float4*)(dst + (e0 + a) * LSTR + j0)     = make_float4(v[a][0], v[a][1], v[a][2], v[a][3]);
    *(float4*)(dst + (e0 + a) * LSTR + j0 + 4) = make_float4(v[a][4], v[a][5], v[a][6], v[a][7]);
  }
}

__device__ __forceinline__ void read_tile(const float* __restrict__ src, float v[2][8], int e0, int j0) {
#pragma unroll
  for (int a = 0; a < 2; ++a) {
    float4 u0 = *(const float4*)(src + (e0 + a) * LSTR + j0);
    float4 u1 = *(const float4*)(src + (e0 + a) * LSTR + j0 + 4);
    v[a][0] = u0.x; v[a][1] = u0.y; v[a][2] = u0.z; v[a][3] = u0.w;
    v[a][4] = u1.x; v[a][5] = u1.y; v[a][6] = u1.z; v[a][7] = u1.w;
  }
}

// -------- K1: x_up_raw[e] += x1[t] for idx_ji[t]==e --------
__global__ void __launch_bounds__(256) k_xup(const float* __restrict__ x1,
                                             const int* __restrict__ idx_ji,
                                             float* __restrict__ out) {
  size_t gid = (size_t)blockIdx.x * 256 + threadIdx.x;   // T_N*32 threads
  int t = (int)(gid >> 5);
  int c = (int)(gid & 31) << 2;
  int e = idx_ji[t];
  float4 v = *(const float4*)(x1 + (size_t)t * 128 + c);
  float* dst = out + (size_t)e * 128 + c;
  atomicAdd(dst + 0, v.x);
  atomicAdd(dst + 1, v.y);
  atomicAdd(dst + 2, v.z);
  atomicAdd(dst + 3, v.w);
}

// -------- Phase A: x_kj_down = silu( (silu(x_old@W_kj+b_kj) * rbf) @ W_down + b_down ) --------
__global__ void __launch_bounds__(NTHR) phaseA(
    const float* __restrict__ x_old, const float* __restrict__ rbf0,
    const float* __restrict__ W_rbf1, const float* __restrict__ W_rbf2,
    const float* __restrict__ W_kj, const float* __restrict__ b_kj,
    const float* __restrict__ W_down, const float* __restrict__ b_down,
    float* __restrict__ xkjdown) {
  extern __shared__ float sm[];
  float* X = sm;
  float* Y = sm + TILE_E * LSTR;
  float* Wl = sm + 2 * TILE_E * LSTR;
  int tid = threadIdx.x;
  size_t e_base = (size_t)blockIdx.x * TILE_E;
  int j0 = (tid & 15) * 8, e0 = (tid >> 4) * 2;
  float acc[2][8], val[2][8];

  load_x_tile(x_old + e_base * 128, X, 128);
  mm_n128(X, W_kj, b_kj, Wl, acc, 128, e0, j0);
#pragma unroll
  for (int a = 0; a < 2; ++a) {
    size_t e = e_base + e0 + a;
    float r6[6];
#pragma unroll
    for (int r = 0; r < 6; ++r) r6[r] = rbf0[e * 6 + r];
    float t8[8];
#pragma unroll
    for (int bb = 0; bb < 8; ++bb) {
      float s = 0.f;
#pragma unroll
      for (int r = 0; r < 6; ++r) s += r6[r] * W_rbf1[r * 8 + bb];
      t8[bb] = s;
    }
#pragma unroll
    for (int c = 0; c < 8; ++c) {
      float rv = 0.f;
#pragma unroll
      for (int bb = 0; bb < 8; ++bb) rv += t8[bb] * W_rbf2[bb * 128 + j0 + c];
      val[a][c] = silu_f(acc[a][c]) * rv;
    }
  }
  __syncthreads();
  store_tile(Y, val, e0, j0);

  int j0d = (tid & 7) * 8, ed = tid >> 3;
  float a8[8];
  mm_n64(Y, W_down, b_down, Wl, a8, ed, j0d);
  float4 o0 = make_float4(silu_f(a8[0]), silu_f(a8[1]), silu_f(a8[2]), silu_f(a8[3]));
  float4 o1 = make_float4(silu_f(a8[4]), silu_f(a8[5]), silu_f(a8[6]), silu_f(a8[7]));
  *(float4*)(xkjdown + (e_base + ed) * 64 + j0d)     = o0;
  *(float4*)(xkjdown + (e_base + ed) * 64 + j0d + 4) = o1;
}

// -------- Phase B: agg[ji] += sbf_p[t] * xkjdown[kj] --------
__global__ void __launch_bounds__(256) phaseB(
    const float* __restrict__ sbf, const float* __restrict__ xkjdown,
    const int* __restrict__ idx_kj, const int* __restrict__ idx_ji,
    const float* __restrict__ W_sbf1, const float* __restrict__ W_sbf2,
    float* __restrict__ agg) {
  __shared__ float s_s[4][42];
  __shared__ float s_t8[4][8];
  int t0 = blockIdx.x * 4;
  for (int i = threadIdx.x; i < 4 * 42; i += 256)
    s_s[i / 42][i % 42] = sbf[(size_t)t0 * 42 + i];
  __syncthreads();
  if (threadIdx.x < 32) {
    int w4 = threadIdx.x >> 3, bb = threadIdx.x & 7;
    float s = 0.f;
#pragma unroll
    for (int r = 0; r < 42; ++r) s += s_s[w4][r] * W_sbf1[r * 8 + bb];
    s_t8[w4][bb] = s;
  }
  __syncthreads();
  int w4 = threadIdx.x >> 6, j = threadIdx.x & 63;
  int t = t0 + w4;
  float sp = 0.f;
#pragma unroll
  for (int bb = 0; bb < 8; ++bb) sp += s_t8[w4][bb] * W_sbf2[bb * 64 + j];
  int kj = idx_kj[t], ji = idx_ji[t];
  float v = sp * xkjdown[(size_t)kj * 64 + j];
  atomicAdd(agg + (size_t)ji * 64 + j, v);
}

// -------- Phase C1: full per-edge GEMM chain, writes e1 --------
__global__ void __launch_bounds__(NTHR) phaseC1(
    const float* __restrict__ x_old,
    float* __restrict__ e1buf,            // in: x_up_raw ; out: e1
    const float* __restrict__ agg,
    const float* __restrict__ W_up, const float* __restrict__ b_up,
    const float* __restrict__ W_ji, const float* __restrict__ b_ji,
    const float* __restrict__ W_get_up, const float* __restrict__ b_get_up,
    const float* __restrict__ W_connect, const float* __restrict__ b_connect,
    const float* __restrict__ rbW, const float* __restrict__ rbB,
    const float* __restrict__ W_lin, const float* __restrict__ b_lin,
    const float* __restrict__ raW, const float* __restrict__ raB) {
  extern __shared__ float sm[];
  float* X = sm;
  float* Y = sm + TILE_E * LSTR;
  float* Wl = sm + 2 * TILE_E * LSTR;
  int tid = threadIdx.x;
  size_t e_base = (size_t)blockIdx.x * TILE_E;
  int j0 = (tid & 15) * 8, e0 = (tid >> 4) * 2;
  float acc[2][8], keep[2][8], tmp[2][8], rd[2][8];

  // S1: t_kj2 = silu(agg @ W_up + b_up)   (K=64)
  load_x_tile(agg + e_base * 64, X, 64);
  mm_n128(X, W_up, b_up, Wl, acc, 64, e0, j0);
#pragma unroll
  for (int a = 0; a < 2; ++a)
#pragma unroll
    for (int c = 0; c < 8; ++c) keep[a][c] = silu_f(acc[a][c]);

  // S2: e1 = silu(x_old@W_ji + b_ji) + t_kj2 -> Y
  __syncthreads();
  load_x_tile(x_old + e_base * 128, X, 128);
  mm_n128(X, W_ji, b_ji, Wl, acc, 128, e0, j0);
#pragma unroll
  for (int a = 0; a < 2; ++a)
#pragma unroll
    for (int c = 0; c < 8; ++c) tmp[a][c] = silu_f(acc[a][c]) + keep[a][c];
  __syncthreads();
  store_tile(Y, tmp, e0, j0);

  // S3: x_up = silu(x_up_raw @ W_get_up + b)  (keep in regs)
  __syncthreads();
  load_x_tile(e1buf + e_base * 128, X, 128);
  mm_n128(X, W_get_up, b_get_up, Wl, acc, 128, e0, j0);
#pragma unroll
  for (int a = 0; a < 2; ++a)
#pragma unroll
    for (int c = 0; c < 8; ++c) keep[a][c] = silu_f(acc[a][c]);

  // S4: e1 = silu(Y@W_connect+b) + x_up -> X
  mm_n128(Y, W_connect, b_connect, Wl, acc, 128, e0, j0);
#pragma unroll
  for (int a = 0; a < 2; ++a)
#pragma unroll
    for (int c = 0; c < 8; ++c) tmp[a][c] = silu_f(acc[a][c]) + keep[a][c];
  __syncthreads();
  store_tile(X, tmp, e0, j0);

  // S5: h = silu(X@rbW0 + rbB0) -> Y
  mm_n128(X, rbW, rbB, Wl, acc, 128, e0, j0);
#pragma unroll
  for (int a = 0; a < 2; ++a)
#pragma unroll
    for (int c = 0; c < 8; ++c) tmp[a][c] = silu_f(acc[a][c]);
  __syncthreads();
  store_tile(Y, tmp, e0, j0);

  // S6: e1 = X + silu(Y@rbW1 + rbB1) -> Y
  mm_n128(Y, rbW + 128 * 128, rbB + 128, Wl, acc, 128, e0, j0);
  read_tile(X, rd, e0, j0);
#pragma unroll
  for (int a = 0; a < 2; ++a)
#pragma unroll
    for (int c = 0; c < 8; ++c) tmp[a][c] = rd[a][c] + silu_f(acc[a][c]);
  __syncthreads();
  store_tile(Y, tmp, e0, j0);

  // S7: e1 = silu(Y@W_lin + b) + x_old -> X
  mm_n128(Y, W_lin, b_lin, Wl, acc, 128, e0, j0);
#pragma unroll
  for (int a = 0; a < 2; ++a) {
    size_t e = e_base + e0 + a;
    float4 x0 = *(const float4*)(x_old + e * 128 + j0);
    float4 x1v = *(const float4*)(x_old + e * 128 + j0 + 4);
    tmp[a][0] = silu_f(acc[a][0]) + x0.x;  tmp[a][1] = silu_f(acc[a][1]) + x0.y;
    tmp[a][2] = silu_f(acc[a][2]) + x0.z;  tmp[a][3] = silu_f(acc[a][3]) + x0.w;
    tmp[a][4] = silu_f(acc[a][4]) + x1v.x; tmp[a][5] = silu_f(acc[a][5]) + x1v.y;
    tmp[a][6] = silu_f(acc[a][6]) + x1v.z; tmp[a][7] = silu_f(acc[a][7]) + x1v.w;
  }
  __syncthreads();
  store_tile(X, tmp, e0, j0);

  // S8: h = silu(X@raW[0][0]) -> Y
  mm_n128(X, raW, raB, Wl, acc, 128, e0, j0);
#pragma unroll
  for (int a = 0; a < 2; ++a)
#pragma unroll
    for (int c = 0; c < 8; ++c) tmp[a][c] = silu_f(acc[a][c]);
  __syncthreads();
  store_tile(Y, tmp, e0, j0);

  // S9: e1 = X + silu(Y@raW[0][1]) -> Y
  mm_n128(Y, raW + 128 * 128, raB + 128, Wl, acc, 128, e0, j0);
  read_tile(X, rd, e0, j0);
#pragma unroll
  for (int a = 0; a < 2; ++a)
#pragma unroll
    for (int c = 0; c < 8; ++c) tmp[a][c] = rd[a][c] + silu_f(acc[a][c]);
  __syncthreads();
  store_tile(Y, tmp, e0, j0);

  // S10: h = silu(Y@raW[1][0]) -> X
  mm_n128(Y, raW + 2 * 128 * 128, raB + 2 * 128, Wl, acc, 128, e0, j0);
#pragma unroll
  for (int a = 0; a < 2; ++a)
#pragma unroll
    for (int c = 0; c < 8; ++c) tmp[a][c] = silu_f(acc[a][c]);
  __syncthreads();
  store_tile(X, tmp, e0, j0);

  // S11: e1_final = Y + silu(X@raW[1][1]) -> global
  mm_n128(X, raW + 3 * 128 * 128, raB + 3 * 128, Wl, acc, 128, e0, j0);
  read_tile(Y, rd, e0, j0);
#pragma unroll
  for (int a = 0; a < 2; ++a) {
    size_t e = e_base + e0 + a;
    float f0 = rd[a][0] + silu_f(acc[a][0]);
    float f1 = rd[a][1] + silu_f(acc[a][1]);
    float f2 = rd[a][2] + silu_f(acc[a][2]);
    float f3 = rd[a][3] + silu_f(acc[a][3]);
    float f4v = rd[a][4] + silu_f(acc[a][4]);
    float f5 = rd[a][5] + silu_f(acc[a][5]);
    float f6 = rd[a][6] + silu_f(acc[a][6]);
    float f7 = rd[a][7] + silu_f(acc[a][7]);
    *(float4*)(e1buf + e * 128 + j0)     = make_float4(f0, f1, f2, f3);
    *(float4*)(e1buf + e * 128 + j0 + 4) = make_float4(f4v, f5, f6, f7);
  }
}

// -------- C2: e2 = (rbf0 @ W_rbf) * e1 --------
__global__ void __launch_bounds__(256) k_e2(const float* __restrict__ e1,
                                            const float* __restrict__ rbf0,
                                            const float* __restrict__ W_rbf,
                                            float* __restrict__ e2) {
  size_t gid = (size_t)blockIdx.x * 256 + threadIdx.x;  // E_N*32
  int e = (int)(gid >> 5);
  int c = (int)(gid & 31) << 2;
  float r6[6];
#pragma unroll
  for (int r = 0; r < 6; ++r) r6[r] = rbf0[(size_t)e * 6 + r];
  float4 v = *(const float4*)(e1 + (size_t)e * 128 + c);
  float4 o;
  float rv;
  rv = 0.f;
#pragma unroll
  for (int r = 0; r < 6; ++r) rv += r6[r] * W_rbf[r * 128 + c + 0];
  o.x = v.x * rv;
  rv = 0.f;
#pragma unroll
  for (int r = 0; r < 6; ++r) rv += r6[r] * W_rbf[r * 128 + c + 1];
  o.y = v.y * rv;
  rv = 0.f;
#pragma unroll
  for (int r = 0; r < 6; ++r) rv += r6[r] * W_rbf[r * 128 + c + 2];
  o.z = v.z * rv;
  rv = 0.f;
#pragma unroll
  for (int r = 0; r < 6; ++r) rv += r6[r] * W_rbf[r * 128 + c + 3];
  o.w = v.w * rv;
  *(float4*)(e2 + (size_t)e * 128 + c) = o;
}

extern "C" void kernel_launch(void* const* d_in, const int* in_sizes, int n_in,
                              void* d_out, int out_size, void* d_ws, size_t ws_size,
                              hipStream_t stream) {
  const float* x1        = (const float*)d_in[0];
  const float* x_old     = (const float*)d_in[1];
  const float* rbf0      = (const float*)d_in[2];
  const float* sbf       = (const float*)d_in[3];
  const int*   idx_kj    = (const int*)d_in[4];
  const int*   idx_ji    = (const int*)d_in[5];
  const float* W_rbf1    = (const float*)d_in[6];
  const float* W_rbf2    = (const float*)d_in[7];
  const float* W_sbf1    = (const float*)d_in[8];
  const float* W_sbf2    = (const float*)d_in[9];
  const float* W_rbf     = (const float*)d_in[10];
  const float* W_kj      = (const float*)d_in[11];
  const float* b_kj      = (const float*)d_in[12];
  const float* W_ji      = (const float*)d_in[13];
  const float* b_ji      = (const float*)d_in[14];
  const float* W_connect = (const float*)d_in[15];
  const float* b_connect = (const float*)d_in[16];
  const float* W_get_up  = (const float*)d_in[17];
  const float* b_get_up  = (const float*)d_in[18];
  const float* W_down    = (const float*)d_in[19];
  const float* b_down    = (const float*)d_in[20];
  const float* W_up      = (const float*)d_in[21];
  const float* b_up      = (const float*)d_in[22];
  const float* rbW       = (const float*)d_in[23];
  const float* rbB       = (const float*)d_in[24];
  const float* W_lin     = (const float*)d_in[25];
  const float* b_lin     = (const float*)d_in[26];
  const float* raW       = (const float*)d_in[27];
  const float* raB       = (const float*)d_in[28];

  float* e1buf   = (float*)d_out;                       // e1 slot; scratch: x_up_raw
  float* e2slot  = e1buf + (size_t)E_N * 128;           // e2 slot
  float* xkjdown = e2slot;                              // [E][64] scratch in e2 slot
  float* agg     = e2slot + (size_t)E_N * 64;           // [E][64] scratch in e2 slot

  // zero accumulators (harness poisons d_out with 0xAA; no re-poison between replays)
  hipMemsetAsync(e1buf, 0, (size_t)E_N * 128 * sizeof(float), stream);
  hipMemsetAsync(agg, 0, (size_t)E_N * 64 * sizeof(float), stream);

  size_t lds_bytes = (size_t)(2 * TILE_E * LSTR + 64 * 128) * sizeof(float);  // ~98 KB

  k_xup<<<T_N * 32 / 256, 256, 0, stream>>>(x1, idx_ji, e1buf);
  phaseA<<<E_N / TILE_E, NTHR, lds_bytes, stream>>>(x_old, rbf0, W_rbf1, W_rbf2,
                                                    W_kj, b_kj, W_down, b_down, xkjdown);
  phaseB<<<T_N / 4, 256, 0, stream>>>(sbf, xkjdown, idx_kj, idx_ji, W_sbf1, W_sbf2, agg);
  phaseC1<<<E_N / TILE_E, NTHR, lds_bytes, stream>>>(x_old, e1buf, agg,
                                                     W_up, b_up, W_ji, b_ji,
                                                     W_get_up, b_get_up, W_connect, b_connect,
                                                     rbW, rbB, W_lin, b_lin, raW, raB);
  k_e2<<<E_N * 32 / 256, 256, 0, stream>>>(e1buf, rbf0, W_rbf, e2slot);
}

// Round 2
// 2824.572 us; speedup vs baseline: 1.7114x; 1.7114x over previous
//
#include <hip/hip_runtime.h>

#define E_N 262144
#define T_N 1048576

typedef short  bf16x8  __attribute__((ext_vector_type(8)));
typedef short  bf16x4v __attribute__((ext_vector_type(4)));
typedef float  f32x4   __attribute__((ext_vector_type(4)));

// weight region offsets (ushort units) inside wreg
#define OFF_KJ    0
#define OFF_DOWN  16384
#define OFF_UP    24576
#define OFF_JI    32768
#define OFF_GU    49152
#define OFF_CN    65536
#define OFF_RB0   81920
#define OFF_RB1   98304
#define OFF_LIN   114688
#define OFF_RA00  131072
#define OFF_RA01  147456
#define OFF_RA10  163840
#define OFF_RA11  180224
#define OFF_END   196608   // W12 (f32[6][128]) follows

__device__ __forceinline__ float silu_f(float x) { return x / (1.0f + __expf(-x)); }

__device__ __forceinline__ unsigned short f2bf(float f) {
  union { float f; unsigned int u; } v; v.f = f;
  unsigned int u = v.u;
  return (unsigned short)((u + 0x7fffu + ((u >> 16) & 1u)) >> 16);   // RNE
}
__device__ __forceinline__ float bf2f(unsigned short h) {
  union { unsigned int u; float f; } v; v.u = ((unsigned int)h) << 16;
  return v.f;
}

// ---- stage [64][NC] f32 global tile -> swizzled bf16 LDS tile (row byte stride NC*2) ----
template<int NC>
__device__ __forceinline__ void stage_tile(const float* __restrict__ g, char* __restrict__ lds) {
  constexpr int RB = NC * 2;
  constexpr int C4 = NC / 4;
  for (int i = threadIdx.x; i < 64 * C4; i += 512) {
    int r = i / C4, c4 = i % C4;
    float4 v = *(const float4*)(g + (size_t)r * NC + c4 * 4);
    bf16x4v h;
    h[0] = (short)f2bf(v.x); h[1] = (short)f2bf(v.y);
    h[2] = (short)f2bf(v.z); h[3] = (short)f2bf(v.w);
    *(bf16x4v*)(lds + r * RB + ((c4 * 8) ^ ((r & 7) << 4))) = h;
  }
}

// ---- MFMA GEMM: lds tile [64][KSTEPS*32] bf16 (swizzled)  @  WT[N][K] bf16 (global) ----
// A-frag: lane l -> row (l&15), k = (l>>4)*8 + j (8 consecutive -> ds_read_b128)
// B-frag: lane l -> col (l&15), same k pattern from WT rows
// C/D:    col = lane&15, row = (lane>>4)*4 + reg   [m89-verified]
template<int MREP, int NREP, int KSTEPS, int RB>
__device__ __forceinline__ void mfma_gemm(const char* __restrict__ lds, int row0, int col0,
                                          const unsigned short* __restrict__ WT, int lane,
                                          f32x4 (&acc)[MREP][NREP]) {
  const int kg = lane >> 4, r15 = lane & 15;
#pragma unroll
  for (int m = 0; m < MREP; ++m)
#pragma unroll
    for (int n = 0; n < NREP; ++n) acc[m][n] = (f32x4){0.f, 0.f, 0.f, 0.f};
#pragma unroll
  for (int kk = 0; kk < KSTEPS; ++kk) {
    bf16x8 a[MREP], bfr[NREP];
#pragma unroll
    for (int m = 0; m < MREP; ++m) {
      int row = row0 + m * 16 + r15;
      a[m] = *(const bf16x8*)(lds + row * RB + ((kk * 64 + kg * 16) ^ ((row & 7) << 4)));
    }
#pragma unroll
    for (int n = 0; n < NREP; ++n) {
      int nc = col0 + n * 16 + r15;
      bfr[n] = *(const bf16x8*)((const short*)WT + nc * (KSTEPS * 32) + kk * 32 + kg * 8);
    }
#pragma unroll
    for (int m = 0; m < MREP; ++m)
#pragma unroll
      for (int n = 0; n < NREP; ++n)
        acc[m][n] = __builtin_amdgcn_mfma_f32_16x16x32_bf16(a[m], bfr[n], acc[m][n], 0, 0, 0);
  }
}

// ---- write 2x2 fragment set (f32) as bf16 into swizzled LDS tile ----
template<int RB>
__device__ __forceinline__ void write_cd(char* __restrict__ lds, int wrow, int wcol, int lane,
                                         const f32x4 (&v)[2][2]) {
  const int kg = lane >> 4, r15 = lane & 15;
#pragma unroll
  for (int m = 0; m < 2; ++m)
#pragma unroll
    for (int n = 0; n < 2; ++n)
#pragma unroll
      for (int r = 0; r < 4; ++r) {
        int row = wrow + m * 16 + kg * 4 + r;
        int col = wcol + n * 16 + r15;
        *(unsigned short*)(lds + row * RB + ((col * 2) ^ ((row & 7) << 4))) = f2bf(v[m][n][r]);
      }
}

// ---- prep: transpose weights to bf16 WT[N][K]; compute W12 = W_rbf1@W_rbf2 (f32) ----
__global__ void __launch_bounds__(256) k_prep(
    const float* __restrict__ W_kj, const float* __restrict__ W_down,
    const float* __restrict__ W_up, const float* __restrict__ W_ji,
    const float* __restrict__ W_get_up, const float* __restrict__ W_connect,
    const float* __restrict__ rbW, const float* __restrict__ W_lin,
    const float* __restrict__ raW,
    const float* __restrict__ W_rbf1, const float* __restrict__ W_rbf2,
    unsigned short* __restrict__ wreg) {
  int b = blockIdx.x;
  if (b == 13) {
    float* W12 = (float*)(wreg + OFF_END);
    for (int i = threadIdx.x; i < 768; i += 256) {
      int r = i >> 7, n = i & 127;
      float s = 0.f;
#pragma unroll
      for (int q = 0; q < 8; ++q) s += W_rbf1[r * 8 + q] * W_rbf2[q * 128 + n];
      W12[i] = s;
    }
    return;
  }
  const float* src; int K = 128, N = 128; int off;
  switch (b) {
    case 0:  src = W_kj;          off = OFF_KJ;  break;
    case 1:  src = W_down;        off = OFF_DOWN; N = 64;  break;
    case 2:  src = W_up;          off = OFF_UP;   K = 64;  break;
    case 3:  src = W_ji;          off = OFF_JI;  break;
    case 4:  src = W_get_up;      off = OFF_GU;  break;
    case 5:  src = W_connect;     off = OFF_CN;  break;
    case 6:  src = rbW;           off = OFF_RB0; break;
    case 7:  src = rbW + 16384;   off = OFF_RB1; break;
    case 8:  src = W_lin;         off = OFF_LIN; break;
    case 9:  src = raW;           off = OFF_RA00; break;
    case 10: src = raW + 16384;   off = OFF_RA01; break;
    case 11: src = raW + 32768;   off = OFF_RA10; break;
    default: src = raW + 49152;   off = OFF_RA11; break;
  }
  unsigned short* dst = wreg + off;
  for (int i = threadIdx.x; i < K * N; i += 256) {
    int k = i / N, n = i % N;
    dst[n * K + k] = f2bf(src[i]);
  }
}

// ---- K1: x_up_raw[e] += x1[t] for idx_ji[t]==e ----
__global__ void __launch_bounds__(256) k_xup(const float* __restrict__ x1,
                                             const int* __restrict__ idx_ji,
                                             float* __restrict__ out) {
  size_t gid = (size_t)blockIdx.x * 256 + threadIdx.x;   // T_N*32 threads
  int t = (int)(gid >> 5);
  int c = (int)(gid & 31) << 2;
  int e = idx_ji[t];
  float4 v = *(const float4*)(x1 + (size_t)t * 128 + c);
  float* dst = out + (size_t)e * 128 + c;
  atomicAdd(dst + 0, v.x);
  atomicAdd(dst + 1, v.y);
  atomicAdd(dst + 2, v.z);
  atomicAdd(dst + 3, v.w);
}

// ---- Phase A: xkjdown = silu( (silu(x_old@W_kj+b) * rbf) @ W_down + b ) -> bf16 ----
__global__ void __launch_bounds__(512, 4) phaseA(
    const float* __restrict__ x_old, const float* __restrict__ rbf0,
    const unsigned short* __restrict__ wreg,
    const float* __restrict__ b_kj, const float* __restrict__ b_down,
    unsigned short* __restrict__ xkjdown) {
  __shared__ char lds[32768];
  char* B0 = lds;
  char* B1 = lds + 16384;
  const int tid = threadIdx.x, lane = tid & 63, wave = tid >> 6;
  const int kg = lane >> 4, r15 = lane & 15;
  const int wrow = (wave >> 2) * 32, wcol = (wave & 3) * 32;
  const size_t e_base = (size_t)blockIdx.x * 64;
  const float* W12 = (const float*)(wreg + OFF_END);

  stage_tile<128>(x_old + e_base * 128, B0);
  __syncthreads();

  f32x4 acc[2][2], val[2][2];
  mfma_gemm<2, 2, 4, 256>(B0, wrow, wcol, wreg + OFF_KJ, lane, acc);
#pragma unroll
  for (int n = 0; n < 2; ++n) {
    int col = wcol + n * 16 + r15;
    float bk = b_kj[col];
    float wc[6];
#pragma unroll
    for (int q = 0; q < 6; ++q) wc[q] = W12[q * 128 + col];
#pragma unroll
    for (int m = 0; m < 2; ++m)
#pragma unroll
      for (int r = 0; r < 4; ++r) {
        int row = wrow + m * 16 + kg * 4 + r;
        const float* rp = rbf0 + (e_base + row) * 6;
        float rv = rp[0]*wc[0] + rp[1]*wc[1] + rp[2]*wc[2] + rp[3]*wc[3] + rp[4]*wc[4] + rp[5]*wc[5];
        val[m][n][r] = silu_f(acc[m][n][r] + bk) * rv;
      }
  }
  __syncthreads();
  write_cd<256>(B1, wrow, wcol, lane, val);
  __syncthreads();

  // N=64 GEMM: waves 4(M) x 2(N)
  const int wrow2 = (wave >> 1) * 16, wcol2 = (wave & 1) * 32;
  f32x4 a2[1][2];
  mfma_gemm<1, 2, 4, 256>(B1, wrow2, wcol2, wreg + OFF_DOWN, lane, a2);
#pragma unroll
  for (int n = 0; n < 2; ++n) {
    int col = wcol2 + n * 16 + r15;
    float bd = b_down[col];
#pragma unroll
    for (int r = 0; r < 4; ++r) {
      int row = wrow2 + kg * 4 + r;
      xkjdown[(e_base + row) * 64 + col] = f2bf(silu_f(a2[0][n][r] + bd));
    }
  }
}

// ---- Phase B: agg[ji] += sbf_p[t] * xkjdown[kj]  (xkjdown bf16) ----
__global__ void __launch_bounds__(256) phaseB(
    const float* __restrict__ sbf, const unsigned short* __restrict__ xkjdown,
    const int* __restrict__ idx_kj, const int* __restrict__ idx_ji,
    const float* __restrict__ W_sbf1, const float* __restrict__ W_sbf2,
    float* __restrict__ agg) {
  __shared__ float s_s[4][42];
  __shared__ float s_t8[4][8];
  int t0 = blockIdx.x * 4;
  for (int i = threadIdx.x; i < 4 * 42; i += 256)
    s_s[i / 42][i % 42] = sbf[(size_t)t0 * 42 + i];
  __syncthreads();
  if (threadIdx.x < 32) {
    int w4 = threadIdx.x >> 3, bb = threadIdx.x & 7;
    float s = 0.f;
#pragma unroll
    for (int r = 0; r < 42; ++r) s += s_s[w4][r] * W_sbf1[r * 8 + bb];
    s_t8[w4][bb] = s;
  }
  __syncthreads();
  int w4 = threadIdx.x >> 6, j = threadIdx.x & 63;
  int t = t0 + w4;
  float sp = 0.f;
#pragma unroll
  for (int bb = 0; bb < 8; ++bb) sp += s_t8[w4][bb] * W_sbf2[bb * 64 + j];
  int kj = idx_kj[t], ji = idx_ji[t];
  float v = sp * bf2f(xkjdown[(size_t)kj * 64 + j]);
  atomicAdd(agg + (size_t)ji * 64 + j, v);
}

// ---- Phase C1: full per-edge GEMM chain (MFMA), writes e1 (f32) ----
__global__ void __launch_bounds__(512, 4) phaseC1(
    const float* __restrict__ x_old, float* __restrict__ e1buf,
    const float* __restrict__ agg, const unsigned short* __restrict__ wreg,
    const float* __restrict__ b_up, const float* __restrict__ b_ji,
    const float* __restrict__ b_get_up, const float* __restrict__ b_connect,
    const float* __restrict__ rbB, const float* __restrict__ b_lin,
    const float* __restrict__ raB) {
  __shared__ char lds[32768];
  char* B0 = lds;
  char* B1 = lds + 16384;
  const int tid = threadIdx.x, lane = tid & 63, wave = tid >> 6;
  const int kg = lane >> 4, r15 = lane & 15;
  const int wrow = (wave >> 2) * 32, wcol = (wave & 3) * 32;
  const size_t e_base = (size_t)blockIdx.x * 64;

  stage_tile<64>(agg + e_base * 64, B0);          // [64][64] RB=128
  stage_tile<128>(x_old + e_base * 128, B1);
  __syncthreads();

  f32x4 acc[2][2], acc2[2][2], keep[2][2], tmp[2][2];

  // S1+S2: e1a = silu(x_old@W_ji+b_ji) + silu(agg@W_up+b_up)
  mfma_gemm<2, 2, 2, 128>(B0, wrow, wcol, wreg + OFF_UP, lane, acc);
  mfma_gemm<2, 2, 4, 256>(B1, wrow, wcol, wreg + OFF_JI, lane, acc2);
#pragma unroll
  for (int n = 0; n < 2; ++n) {
    int col = wcol + n * 16 + r15;
    float bu = b_up[col], bj = b_ji[col];
#pragma unroll
    for (int m = 0; m < 2; ++m)
#pragma unroll
      for (int r = 0; r < 4; ++r)
        keep[m][n][r] = silu_f(acc2[m][n][r] + bj) + silu_f(acc[m][n][r] + bu);
  }
  __syncthreads();
  write_cd<256>(B0, wrow, wcol, lane, keep);          // e1a -> B0
  stage_tile<128>(e1buf + e_base * 128, B1);          // x_up_raw -> B1
  __syncthreads();

  // S3+S4: e1b = silu(e1a@W_connect+b) + silu(x_up_raw@W_get_up+b)
  mfma_gemm<2, 2, 4, 256>(B1, wrow, wcol, wreg + OFF_GU, lane, acc);
  mfma_gemm<2, 2, 4, 256>(B0, wrow, wcol, wreg + OFF_CN, lane, acc2);
#pragma unroll
  for (int n = 0; n < 2; ++n) {
    int col = wcol + n * 16 + r15;
    float bg = b_get_up[col], bc = b_connect[col];
#pragma unroll
    for (int m = 0; m < 2; ++m)
#pragma unroll
      for (int r = 0; r < 4; ++r)
        keep[m][n][r] = silu_f(acc2[m][n][r] + bc) + silu_f(acc[m][n][r] + bg);
  }
  __syncthreads();
  write_cd<256>(B1, wrow, wcol, lane, keep);          // e1b -> B1
  __syncthreads();

  // S5: h = silu(e1b@rb0 + b) -> B0
  mfma_gemm<2, 2, 4, 256>(B1, wrow, wcol, wreg + OFF_RB0, lane, acc);
#pragma unroll
  for (int n = 0; n < 2; ++n) {
    float b0v = rbB[wcol + n * 16 + r15];
#pragma unroll
    for (int m = 0; m < 2; ++m)
#pragma unroll
      for (int r = 0; r < 4; ++r) tmp[m][n][r] = silu_f(acc[m][n][r] + b0v);
  }
  __syncthreads();
  write_cd<256>(B0, wrow, wcol, lane, tmp);
  __syncthreads();

  // S6: e1c = e1b + silu(h@rb1 + b) -> B1
  mfma_gemm<2, 2, 4, 256>(B0, wrow, wcol, wreg + OFF_RB1, lane, acc);
#pragma unroll
  for (int n = 0; n < 2; ++n) {
    float b1v = rbB[128 + wcol + n * 16 + r15];
#pragma unroll
    for (int m = 0; m < 2; ++m)
#pragma unroll
      for (int r = 0; r < 4; ++r) keep[m][n][r] += silu_f(acc[m][n][r] + b1v);
  }
  __syncthreads();
  write_cd<256>(B1, wrow, wcol, lane, keep);
  __syncthreads();

  // S7: e1d = silu(e1c@W_lin + b) + x_old -> B0
  mfma_gemm<2, 2, 4, 256>(B1, wrow, wcol, wreg + OFF_LIN, lane, acc);
#pragma unroll
  for (int n = 0; n < 2; ++n) {
    int col = wcol + n * 16 + r15;
    float bl = b_lin[col];
#pragma unroll
    for (int m = 0; m < 2; ++m)
#pragma unroll
      for (int r = 0; r < 4; ++r) {
        int row = wrow + m * 16 + kg * 4 + r;
        keep[m][n][r] = silu_f(acc[m][n][r] + bl) + x_old[(e_base + row) * 128 + col];
      }
  }
  __syncthreads();
  write_cd<256>(B0, wrow, wcol, lane, keep);
  __syncthreads();

  // S8: h = silu(e1d@ra00 + b) -> B1
  mfma_gemm<2, 2, 4, 256>(B0, wrow, wcol, wreg + OFF_RA00, lane, acc);
#pragma unroll
  for (int n = 0; n < 2; ++n) {
    float bv = raB[wcol + n * 16 + r15];
#pragma unroll
    for (int m = 0; m < 2; ++m)
#pragma unroll
      for (int r = 0; r < 4; ++r) tmp[m][n][r] = silu_f(acc[m][n][r] + bv);
  }
  __syncthreads();
  write_cd<256>(B1, wrow, wcol, lane, tmp);
  __syncthreads();

  // S9: e1e = e1d + silu(h@ra01 + b) -> B0
  mfma_gemm<2, 2, 4, 256>(B1, wrow, wcol, wreg + OFF_RA01, lane, acc);
#pragma unroll
  for (int n = 0; n < 2; ++n) {
    float bv = raB[128 + wcol + n * 16 + r15];
#pragma unroll
    for (int m = 0; m < 2; ++m)
#pragma unroll
      for (int r = 0; r < 4; ++r) keep[m][n][r] += silu_f(acc[m][n][r] + bv);
  }
  __syncthreads();
  write_cd<256>(B0, wrow, wcol, lane, keep);
  __syncthreads();

  // S10: h = silu(e1e@ra10 + b) -> B1
  mfma_gemm<2, 2, 4, 256>(B0, wrow, wcol, wreg + OFF_RA10, lane, acc);
#pragma unroll
  for (int n = 0; n < 2; ++n) {
    float bv = raB[256 + wcol + n * 16 + r15];
#pragma unroll
    for (int m = 0; m < 2; ++m)
#pragma unroll
      for (int r = 0; r < 4; ++r) tmp[m][n][r] = silu_f(acc[m][n][r] + bv);
  }
  __syncthreads();
  write_cd<256>(B1, wrow, wcol, lane, tmp);
  __syncthreads();

  // S11: e1 = e1e + silu(h@ra11 + b) -> global f32
  mfma_gemm<2, 2, 4, 256>(B1, wrow, wcol, wreg + OFF_RA11, lane, acc);
#pragma unroll
  for (int n = 0; n < 2; ++n) {
    int col = wcol + n * 16 + r15;
    float bv = raB[384 + col];
#pragma unroll
    for (int m = 0; m < 2; ++m)
#pragma unroll
      for (int r = 0; r < 4; ++r) {
        int row = wrow + m * 16 + kg * 4 + r;
        e1buf[(e_base + row) * 128 + col] = keep[m][n][r] + silu_f(acc[m][n][r] + bv);
      }
  }
}

// ---- C2: e2 = (rbf0 @ W_rbf) * e1 ----
__global__ void __launch_bounds__(256) k_e2(const float* __restrict__ e1,
                                            const float* __restrict__ rbf0,
                                            const float* __restrict__ W_rbf,
                                            float* __restrict__ e2) {
  size_t gid = (size_t)blockIdx.x * 256 + threadIdx.x;  // E_N*32
  int e = (int)(gid >> 5);
  int c = (int)(gid & 31) << 2;
  float r6[6];
#pragma unroll
  for (int r = 0; r < 6; ++r) r6[r] = rbf0[(size_t)e * 6 + r];
  float4 v = *(const float4*)(e1 + (size_t)e * 128 + c);
  float4 o;
  float rv;
  rv = 0.f;
#pragma unroll
  for (int r = 0; r < 6; ++r) rv += r6[r] * W_rbf[r * 128 + c + 0];
  o.x = v.x * rv;
  rv = 0.f;
#pragma unroll
  for (int r = 0; r < 6; ++r) rv += r6[r] * W_rbf[r * 128 + c + 1];
  o.y = v.y * rv;
  rv = 0.f;
#pragma unroll
  for (int r = 0; r < 6; ++r) rv += r6[r] * W_rbf[r * 128 + c + 2];
  o.z = v.z * rv;
  rv = 0.f;
#pragma unroll
  for (int r = 0; r < 6; ++r) rv += r6[r] * W_rbf[r * 128 + c + 3];
  o.w = v.w * rv;
  *(float4*)(e2 + (size_t)e * 128 + c) = o;
}

extern "C" void kernel_launch(void* const* d_in, const int* in_sizes, int n_in,
                              void* d_out, int out_size, void* d_ws, size_t ws_size,
                              hipStream_t stream) {
  const float* x1        = (const float*)d_in[0];
  const float* x_old     = (const float*)d_in[1];
  const float* rbf0      = (const float*)d_in[2];
  const float* sbf       = (const float*)d_in[3];
  const int*   idx_kj    = (const int*)d_in[4];
  const int*   idx_ji    = (const int*)d_in[5];
  const float* W_rbf1    = (const float*)d_in[6];
  const float* W_rbf2    = (const float*)d_in[7];
  const float* W_sbf1    = (const float*)d_in[8];
  const float* W_sbf2    = (const float*)d_in[9];
  const float* W_rbf     = (const float*)d_in[10];
  const float* W_kj      = (const float*)d_in[11];
  const float* b_kj      = (const float*)d_in[12];
  const float* W_ji      = (const float*)d_in[13];
  const float* b_ji      = (const float*)d_in[14];
  const float* W_connect = (const float*)d_in[15];
  const float* b_connect = (const float*)d_in[16];
  const float* W_get_up  = (const float*)d_in[17];
  const float* b_get_up  = (const float*)d_in[18];
  const float* W_down    = (const float*)d_in[19];
  const float* b_down    = (const float*)d_in[20];
  const float* W_up      = (const float*)d_in[21];
  const float* b_up      = (const float*)d_in[22];
  const float* rbW       = (const float*)d_in[23];
  const float* rbB       = (const float*)d_in[24];
  const float* W_lin     = (const float*)d_in[25];
  const float* b_lin     = (const float*)d_in[26];
  const float* raW       = (const float*)d_in[27];
  const float* raB       = (const float*)d_in[28];

  float* e1buf  = (float*)d_out;                         // e1 slot; scratch: x_up_raw
  float* e2slot = e1buf + (size_t)E_N * 128;             // e2 slot
  float* agg    = e2slot;                                                  // f32 [E][64]
  unsigned short* xkjdown_b = (unsigned short*)(e2slot + (size_t)E_N * 64); // bf16 [E][64]
  unsigned short* wreg = (unsigned short*)(e2slot + (size_t)E_N * 64 + (size_t)E_N * 32);

  hipMemsetAsync(e1buf, 0, (size_t)E_N * 128 * sizeof(float), stream);
  hipMemsetAsync(agg, 0, (size_t)E_N * 64 * sizeof(float), stream);

  k_prep<<<14, 256, 0, stream>>>(W_kj, W_down, W_up, W_ji, W_get_up, W_connect,
                                 rbW, W_lin, raW, W_rbf1, W_rbf2, wreg);
  k_xup<<<T_N * 32 / 256, 256, 0, stream>>>(x1, idx_ji, e1buf);
  phaseA<<<E_N / 64, 512, 0, stream>>>(x_old, rbf0, wreg, b_kj, b_down, xkjdown_b);
  phaseB<<<T_N / 4, 256, 0, stream>>>(sbf, xkjdown_b, idx_kj, idx_ji, W_sbf1, W_sbf2, agg);
  phaseC1<<<E_N / 64, 512, 0, stream>>>(x_old, e1buf, agg, wreg,
                                        b_up, b_ji, b_get_up, b_connect, rbB, b_lin, raB);
  k_e2<<<E_N * 32 / 256, 256, 0, stream>>>(e1buf, rbf0, W_rbf, e2slot);
}

// Round 4
// 1355.920 us; speedup vs baseline: 3.5650x; 2.0831x over previous
//
#include <hip/hip_runtime.h>

#define E_N 262144
#define T_N 1048576

typedef short  bf16x8  __attribute__((ext_vector_type(8)));
typedef short  bf16x4v __attribute__((ext_vector_type(4)));
typedef float  f32x4   __attribute__((ext_vector_type(4)));

// wreg offsets (ushort units)
#define OFF_KJ    0
#define OFF_DOWN  16384
#define OFF_UP    24576
#define OFF_JI    32768
#define OFF_GU    49152
#define OFF_CN    65536
#define OFF_RB0   81920
#define OFF_RB1   98304
#define OFF_LIN   114688
#define OFF_RA00  131072
#define OFF_RA01  147456
#define OFF_RA10  163840
#define OFF_RA11  180224
#define OFF_END   196608   // W12 (f32[6][128]) follows
#define WREG_BYTES 524288u  // 396,288 rounded up

// byte offsets inside the e2 slot (E_N*128*4 = 134217728 B) — fallback layout
#define OFFB_AGG   0u          // bf16 [E][64]
#define OFFB_XKJ   33554432u   // bf16 [E][64]
#define OFFB_WREG  67108864u   // fallback wreg
#define OFFB_CNT   67633152u   // int [E+1]
#define OFFB_POS   68683776u   // int [E]
#define OFFB_TRI   69732352u   // int [T]
#define OFFB_BS    73926656u   // int [256]
#define OFFB_BP    73927680u   // int [256]

__device__ __forceinline__ float silu_f(float x) { return x / (1.0f + __expf(-x)); }

__device__ __forceinline__ unsigned short f2bf(float f) {
  union { float f; unsigned int u; } v; v.f = f;
  unsigned int u = v.u;
  return (unsigned short)((u + 0x7fffu + ((u >> 16) & 1u)) >> 16);   // RNE
}
__device__ __forceinline__ float bf2f(unsigned short h) {
  union { unsigned int u; float f; } v; v.u = ((unsigned int)h) << 16;
  return v.f;
}

// ---- stage [64][NC] f32 global tile -> swizzled bf16 LDS tile ----
template<int NC>
__device__ __forceinline__ void stage_tile(const float* __restrict__ g, char* __restrict__ lds) {
  constexpr int RB = NC * 2;
  constexpr int C4 = NC / 4;
  for (int i = threadIdx.x; i < 64 * C4; i += 512) {
    int r = i / C4, c4 = i % C4;
    float4 v = *(const float4*)(g + (size_t)r * NC + c4 * 4);
    bf16x4v h;
    h[0] = (short)f2bf(v.x); h[1] = (short)f2bf(v.y);
    h[2] = (short)f2bf(v.z); h[3] = (short)f2bf(v.w);
    *(bf16x4v*)(lds + r * RB + ((c4 * 8) ^ ((r & 7) << 4))) = h;
  }
}

// ---- stage [64][64] bf16 global tile -> swizzled LDS (straight copy) ----
__device__ __forceinline__ void stage_tile_bf16_64(const unsigned short* __restrict__ g,
                                                   char* __restrict__ lds) {
  int i = threadIdx.x;            // 512 threads, 512 16B-chunks
  int r = i >> 3, c = i & 7;
  int4 v = *(const int4*)((const char*)g + r * 128 + c * 16);
  *(int4*)(lds + r * 128 + ((c * 16) ^ ((r & 7) << 4))) = v;
}

// ---- MFMA GEMM: swizzled LDS A-tile  @  WT[N][K] bf16 (global) ----
template<int MREP, int NREP, int KSTEPS, int RB>
__device__ __forceinline__ void mfma_gemm(const char* __restrict__ lds, int row0, int col0,
                                          const unsigned short* __restrict__ WT, int lane,
                                          f32x4 (&acc)[MREP][NREP]) {
  const int kg = lane >> 4, r15 = lane & 15;
#pragma unroll
  for (int m = 0; m < MREP; ++m)
#pragma unroll
    for (int n = 0; n < NREP; ++n) acc[m][n] = (f32x4){0.f, 0.f, 0.f, 0.f};
#pragma unroll
  for (int kk = 0; kk < KSTEPS; ++kk) {
    bf16x8 a[MREP], bfr[NREP];
#pragma unroll
    for (int m = 0; m < MREP; ++m) {
      int row = row0 + m * 16 + r15;
      a[m] = *(const bf16x8*)(lds + row * RB + ((kk * 64 + kg * 16) ^ ((row & 7) << 4)));
    }
#pragma unroll
    for (int n = 0; n < NREP; ++n) {
      int nc = col0 + n * 16 + r15;
      bfr[n] = *(const bf16x8*)((const short*)WT + nc * (KSTEPS * 32) + kk * 32 + kg * 8);
    }
#pragma unroll
    for (int m = 0; m < MREP; ++m)
#pragma unroll
      for (int n = 0; n < NREP; ++n)
        acc[m][n] = __builtin_amdgcn_mfma_f32_16x16x32_bf16(a[m], bfr[n], acc[m][n], 0, 0, 0);
  }
}

template<int RB>
__device__ __forceinline__ void write_cd(char* __restrict__ lds, int wrow, int wcol, int lane,
                                         const f32x4 (&v)[2][2]) {
  const int kg = lane >> 4, r15 = lane & 15;
#pragma unroll
  for (int m = 0; m < 2; ++m)
#pragma unroll
    for (int n = 0; n < 2; ++n)
#pragma unroll
      for (int r = 0; r < 4; ++r) {
        int row = wrow + m * 16 + kg * 4 + r;
        int col = wcol + n * 16 + r15;
        *(unsigned short*)(lds + row * RB + ((col * 2) ^ ((row & 7) << 4))) = f2bf(v[m][n][r]);
      }
}

// ---- prep: transpose weights to bf16 WT[N][K]; W12 = W_rbf1@W_rbf2 ----
__global__ void __launch_bounds__(256) k_prep(
    const float* __restrict__ W_kj, const float* __restrict__ W_down,
    const float* __restrict__ W_up, const float* __restrict__ W_ji,
    const float* __restrict__ W_get_up, const float* __restrict__ W_connect,
    const float* __restrict__ rbW, const float* __restrict__ W_lin,
    const float* __restrict__ raW,
    const float* __restrict__ W_rbf1, const float* __restrict__ W_rbf2,
    unsigned short* __restrict__ wreg) {
  int b = blockIdx.x;
  if (b == 13) {
    float* W12 = (float*)(wreg + OFF_END);
    for (int i = threadIdx.x; i < 768; i += 256) {
      int r = i >> 7, n = i & 127;
      float s = 0.f;
#pragma unroll
      for (int q = 0; q < 8; ++q) s += W_rbf1[r * 8 + q] * W_rbf2[q * 128 + n];
      W12[i] = s;
    }
    return;
  }
  const float* src; int K = 128, N = 128; int off;
  switch (b) {
    case 0:  src = W_kj;          off = OFF_KJ;  break;
    case 1:  src = W_down;        off = OFF_DOWN; N = 64;  break;
    case 2:  src = W_up;          off = OFF_UP;   K = 64;  break;
    case 3:  src = W_ji;          off = OFF_JI;  break;
    case 4:  src = W_get_up;      off = OFF_GU;  break;
    case 5:  src = W_connect;     off = OFF_CN;  break;
    case 6:  src = rbW;           off = OFF_RB0; break;
    case 7:  src = rbW + 16384;   off = OFF_RB1; break;
    case 8:  src = W_lin;         off = OFF_LIN; break;
    case 9:  src = raW;           off = OFF_RA00; break;
    case 10: src = raW + 16384;   off = OFF_RA01; break;
    case 11: src = raW + 32768;   off = OFF_RA10; break;
    default: src = raW + 49152;   off = OFF_RA11; break;
  }
  unsigned short* dst = wreg + off;
  for (int i = threadIdx.x; i < K * N; i += 256) {
    int k = i / N, n = i % N;
    dst[n * K + k] = f2bf(src[i]);
  }
}

// ================= CSR build (by idx_ji) =================
__global__ void __launch_bounds__(256) k_hist(const int* __restrict__ idx_ji,
                                              int* __restrict__ counts) {
  int t = blockIdx.x * 256 + threadIdx.x;
  atomicAdd(&counts[idx_ji[t]], 1);
}

// reads counts -> writes block-local exclusive prefix into locpre (separate buffer)
__global__ void __launch_bounds__(1024) k_scan1(const int* __restrict__ counts,
                                                int* __restrict__ locpre,
                                                int* __restrict__ bsum) {
  __shared__ int s[1024];
  int i = blockIdx.x * 1024 + threadIdx.x;
  int v = counts[i];
  s[threadIdx.x] = v; __syncthreads();
  for (int o = 1; o < 1024; o <<= 1) {
    int t = (threadIdx.x >= o) ? s[threadIdx.x - o] : 0;
    __syncthreads();
    s[threadIdx.x] += t;
    __syncthreads();
  }
  locpre[i] = s[threadIdx.x] - v;
  if (threadIdx.x == 1023) bsum[blockIdx.x] = s[1023];
}

__global__ void __launch_bounds__(256) k_scan2(const int* __restrict__ bsum,
                                               int* __restrict__ bpre, int* __restrict__ offs) {
  __shared__ int s[256];
  int v = bsum[threadIdx.x];
  s[threadIdx.x] = v; __syncthreads();
  for (int o = 1; o < 256; o <<= 1) {
    int t = (threadIdx.x >= o) ? s[threadIdx.x - o] : 0;
    __syncthreads();
    s[threadIdx.x] += t;
    __syncthreads();
  }
  bpre[threadIdx.x] = s[threadIdx.x] - v;
  if (threadIdx.x == 0) offs[E_N] = T_N;
}

// locpre + bpre -> final exclusive offsets, written to offs AND pos
__global__ void __launch_bounds__(1024) k_scan3(const int* __restrict__ locpre,
                                                const int* __restrict__ bpre,
                                                int* __restrict__ offs,
                                                int* __restrict__ pos) {
  int i = blockIdx.x * 1024 + threadIdx.x;
  int v = locpre[i] + bpre[blockIdx.x];
  offs[i] = v;
  pos[i] = v;
}

__global__ void __launch_bounds__(256) k_fill(const int* __restrict__ idx_ji,
                                              int* __restrict__ pos, int* __restrict__ tri) {
  int t = blockIdx.x * 256 + threadIdx.x;
  int e = idx_ji[t];
  int slot = atomicAdd(&pos[e], 1);
  tri[slot] = t;
}

// ================= dense sbf_p: [T][64] bf16 =================
__global__ void __launch_bounds__(256) k_sbfp(const float* __restrict__ sbf,
                                              const float* __restrict__ W_sbf1,
                                              const float* __restrict__ W_sbf2,
                                              unsigned int* __restrict__ sbfp) {
  __shared__ float s_s[8][42];
  __shared__ float s_t8[8][8];
  int t0 = blockIdx.x * 8;
  for (int i = threadIdx.x; i < 8 * 42; i += 256)
    s_s[i / 42][i % 42] = sbf[(size_t)t0 * 42 + i];
  __syncthreads();
  if (threadIdx.x < 64) {
    int w8 = threadIdx.x >> 3, bb = threadIdx.x & 7;
    float s = 0.f;
#pragma unroll
    for (int r = 0; r < 42; ++r) s += s_s[w8][r] * W_sbf1[r * 8 + bb];
    s_t8[w8][bb] = s;
  }
  __syncthreads();
  int w8 = threadIdx.x >> 5, jj = threadIdx.x & 31;
  float sp0 = 0.f, sp1 = 0.f;
#pragma unroll
  for (int bb = 0; bb < 8; ++bb) {
    float tv = s_t8[w8][bb];
    sp0 += tv * W_sbf2[bb * 64 + jj * 2];
    sp1 += tv * W_sbf2[bb * 64 + jj * 2 + 1];
  }
  unsigned int u = (unsigned int)f2bf(sp0) | ((unsigned int)f2bf(sp1) << 16);
  sbfp[(size_t)(t0 + w8) * 32 + jj] = u;
}

// ================= gather: agg[e][j] = sum_t sbfp[t][j]*xkj[idx_kj[t]][j] =================
__global__ void __launch_bounds__(256) k_aggB(const int* __restrict__ offs,
                                              const int* __restrict__ tri,
                                              const int* __restrict__ idx_kj,
                                              const unsigned int* __restrict__ sbfp,
                                              const unsigned int* __restrict__ xkj,
                                              unsigned int* __restrict__ agg) {
  int sub = threadIdx.x >> 5, jj = threadIdx.x & 31;   // 8 edges/block, 32 lanes * 2 cols
  int e = blockIdx.x * 8 + sub;
  int o0 = offs[e], o1 = offs[e + 1];
  float a0 = 0.f, a1 = 0.f;
  for (int i = o0; i < o1; ++i) {
    int t = tri[i];
    int kj = idx_kj[t];
    unsigned int sv = sbfp[(size_t)t * 32 + jj];
    unsigned int xv = xkj[(size_t)kj * 32 + jj];
    a0 += bf2f((unsigned short)(sv & 0xffff)) * bf2f((unsigned short)(xv & 0xffff));
    a1 += bf2f((unsigned short)(sv >> 16)) * bf2f((unsigned short)(xv >> 16));
  }
  agg[(size_t)e * 32 + jj] = (unsigned int)f2bf(a0) | ((unsigned int)f2bf(a1) << 16);
}

// ================= gather: x_up_raw[e][h] = sum_t x1[t][h] =================
__global__ void __launch_bounds__(256) k_xupg(const int* __restrict__ offs,
                                              const int* __restrict__ tri,
                                              const float* __restrict__ x1,
                                              float* __restrict__ out) {
  int sub = threadIdx.x >> 6, h2 = threadIdx.x & 63;   // 4 edges/block, 64 lanes * float2
  int e = blockIdx.x * 4 + sub;
  int o0 = offs[e], o1 = offs[e + 1];
  float a0 = 0.f, a1 = 0.f;
  for (int i = o0; i < o1; ++i) {
    int t = tri[i];
    float2 v = *(const float2*)(x1 + (size_t)t * 128 + h2 * 2);
    a0 += v.x; a1 += v.y;
  }
  *(float2*)(out + (size_t)e * 128 + h2 * 2) = make_float2(a0, a1);
}

// ================= Phase A =================
__global__ void __launch_bounds__(512, 4) phaseA(
    const float* __restrict__ x_old, const float* __restrict__ rbf0,
    const unsigned short* __restrict__ wreg,
    const float* __restrict__ b_kj, const float* __restrict__ b_down,
    unsigned short* __restrict__ xkjdown) {
  __shared__ char lds[32768];
  char* B0 = lds;
  char* B1 = lds + 16384;
  const int tid = threadIdx.x, lane = tid & 63, wave = tid >> 6;
  const int kg = lane >> 4, r15 = lane & 15;
  const int wrow = (wave >> 2) * 32, wcol = (wave & 3) * 32;
  const size_t e_base = (size_t)blockIdx.x * 64;
  const float* W12 = (const float*)(wreg + OFF_END);

  stage_tile<128>(x_old + e_base * 128, B0);
  __syncthreads();

  f32x4 acc[2][2], val[2][2];
  mfma_gemm<2, 2, 4, 256>(B0, wrow, wcol, wreg + OFF_KJ, lane, acc);
#pragma unroll
  for (int n = 0; n < 2; ++n) {
    int col = wcol + n * 16 + r15;
    float bk = b_kj[col];
    float wc[6];
#pragma unroll
    for (int q = 0; q < 6; ++q) wc[q] = W12[q * 128 + col];
#pragma unroll
    for (int m = 0; m < 2; ++m)
#pragma unroll
      for (int r = 0; r < 4; ++r) {
        int row = wrow + m * 16 + kg * 4 + r;
        const float* rp = rbf0 + (e_base + row) * 6;
        float rv = rp[0]*wc[0] + rp[1]*wc[1] + rp[2]*wc[2] + rp[3]*wc[3] + rp[4]*wc[4] + rp[5]*wc[5];
        val[m][n][r] = silu_f(acc[m][n][r] + bk) * rv;
      }
  }
  __syncthreads();
  write_cd<256>(B1, wrow, wcol, lane, val);
  __syncthreads();

  const int wrow2 = (wave >> 1) * 16, wcol2 = (wave & 1) * 32;
  f32x4 a2[1][2];
  mfma_gemm<1, 2, 4, 256>(B1, wrow2, wcol2, wreg + OFF_DOWN, lane, a2);
#pragma unroll
  for (int n = 0; n < 2; ++n) {
    int col = wcol2 + n * 16 + r15;
    float bd = b_down[col];
#pragma unroll
    for (int r = 0; r < 4; ++r) {
      int row = wrow2 + kg * 4 + r;
      xkjdown[(e_base + row) * 64 + col] = f2bf(silu_f(a2[0][n][r] + bd));
    }
  }
}

// ================= Phase C1: GEMM chain, writes e1 (+fused e2 if e2o) =================
__global__ void __launch_bounds__(512, 4) phaseC1(
    const float* __restrict__ x_old, float* __restrict__ e1buf,
    const unsigned short* __restrict__ agg, const unsigned short* __restrict__ wreg,
    const float* __restrict__ b_up, const float* __restrict__ b_ji,
    const float* __restrict__ b_get_up, const float* __restrict__ b_connect,
    const float* __restrict__ rbB, const float* __restrict__ b_lin,
    const float* __restrict__ raB,
    const float* __restrict__ rbf0, const float* __restrict__ W_rbf,
    float* __restrict__ e2o) {
  __shared__ char lds[32768];
  char* B0 = lds;
  char* B1 = lds + 16384;
  const int tid = threadIdx.x, lane = tid & 63, wave = tid >> 6;
  const int kg = lane >> 4, r15 = lane & 15;
  const int wrow = (wave >> 2) * 32, wcol = (wave & 3) * 32;
  const size_t e_base = (size_t)blockIdx.x * 64;

  stage_tile_bf16_64(agg + e_base * 64, B0);      // [64][64] bf16, RB=128
  stage_tile<128>(x_old + e_base * 128, B1);
  __syncthreads();

  f32x4 acc[2][2], acc2[2][2], keep[2][2], tmp[2][2];

  // S1+S2: e1a = silu(x_old@W_ji+b_ji) + silu(agg@W_up+b_up)
  mfma_gemm<2, 2, 2, 128>(B0, wrow, wcol, wreg + OFF_UP, lane, acc);
  mfma_gemm<2, 2, 4, 256>(B1, wrow, wcol, wreg + OFF_JI, lane, acc2);
#pragma unroll
  for (int n = 0; n < 2; ++n) {
    int col = wcol + n * 16 + r15;
    float bu = b_up[col], bj = b_ji[col];
#pragma unroll
    for (int m = 0; m < 2; ++m)
#pragma unroll
      for (int r = 0; r < 4; ++r)
        keep[m][n][r] = silu_f(acc2[m][n][r] + bj) + silu_f(acc[m][n][r] + bu);
  }
  __syncthreads();
  write_cd<256>(B0, wrow, wcol, lane, keep);
  stage_tile<128>(e1buf + e_base * 128, B1);          // x_up_raw
  __syncthreads();

  // S3+S4: e1b = silu(e1a@W_connect+b) + silu(x_up_raw@W_get_up+b)
  mfma_gemm<2, 2, 4, 256>(B1, wrow, wcol, wreg + OFF_GU, lane, acc);
  mfma_gemm<2, 2, 4, 256>(B0, wrow, wcol, wreg + OFF_CN, lane, acc2);
#pragma unroll
  for (int n = 0; n < 2; ++n) {
    int col = wcol + n * 16 + r15;
    float bg = b_get_up[col], bc = b_connect[col];
#pragma unroll
    for (int m = 0; m < 2; ++m)
#pragma unroll
      for (int r = 0; r < 4; ++r)
        keep[m][n][r] = silu_f(acc2[m][n][r] + bc) + silu_f(acc[m][n][r] + bg);
  }
  __syncthreads();
  write_cd<256>(B1, wrow, wcol, lane, keep);
  __syncthreads();

  // S5: h = silu(e1b@rb0 + b) -> B0
  mfma_gemm<2, 2, 4, 256>(B1, wrow, wcol, wreg + OFF_RB0, lane, acc);
#pragma unroll
  for (int n = 0; n < 2; ++n) {
    float b0v = rbB[wcol + n * 16 + r15];
#pragma unroll
    for (int m = 0; m < 2; ++m)
#pragma unroll
      for (int r = 0; r < 4; ++r) tmp[m][n][r] = silu_f(acc[m][n][r] + b0v);
  }
  __syncthreads();
  write_cd<256>(B0, wrow, wcol, lane, tmp);
  __syncthreads();

  // S6: e1c = e1b + silu(h@rb1 + b) -> B1
  mfma_gemm<2, 2, 4, 256>(B0, wrow, wcol, wreg + OFF_RB1, lane, acc);
#pragma unroll
  for (int n = 0; n < 2; ++n) {
    float b1v = rbB[128 + wcol + n * 16 + r15];
#pragma unroll
    for (int m = 0; m < 2; ++m)
#pragma unroll
      for (int r = 0; r < 4; ++r) keep[m][n][r] += silu_f(acc[m][n][r] + b1v);
  }
  __syncthreads();
  write_cd<256>(B1, wrow, wcol, lane, keep);
  __syncthreads();

  // S7: e1d = silu(e1c@W_lin + b) + x_old -> B0
  mfma_gemm<2, 2, 4, 256>(B1, wrow, wcol, wreg + OFF_LIN, lane, acc);
#pragma unroll
  for (int n = 0; n < 2; ++n) {
    int col = wcol + n * 16 + r15;
    float bl = b_lin[col];
#pragma unroll
    for (int m = 0; m < 2; ++m)
#pragma unroll
      for (int r = 0; r < 4; ++r) {
        int row = wrow + m * 16 + kg * 4 + r;
        keep[m][n][r] = silu_f(acc[m][n][r] + bl) + x_old[(e_base + row) * 128 + col];
      }
  }
  __syncthreads();
  write_cd<256>(B0, wrow, wcol, lane, keep);
  __syncthreads();

  // S8: h = silu(e1d@ra00 + b) -> B1
  mfma_gemm<2, 2, 4, 256>(B0, wrow, wcol, wreg + OFF_RA00, lane, acc);
#pragma unroll
  for (int n = 0; n < 2; ++n) {
    float bv = raB[wcol + n * 16 + r15];
#pragma unroll
    for (int m = 0; m < 2; ++m)
#pragma unroll
      for (int r = 0; r < 4; ++r) tmp[m][n][r] = silu_f(acc[m][n][r] + bv);
  }
  __syncthreads();
  write_cd<256>(B1, wrow, wcol, lane, tmp);
  __syncthreads();

  // S9: e1e = e1d + silu(h@ra01 + b) -> B0
  mfma_gemm<2, 2, 4, 256>(B1, wrow, wcol, wreg + OFF_RA01, lane, acc);
#pragma unroll
  for (int n = 0; n < 2; ++n) {
    float bv = raB[128 + wcol + n * 16 + r15];
#pragma unroll
    for (int m = 0; m < 2; ++m)
#pragma unroll
      for (int r = 0; r < 4; ++r) keep[m][n][r] += silu_f(acc[m][n][r] + bv);
  }
  __syncthreads();
  write_cd<256>(B0, wrow, wcol, lane, keep);
  __syncthreads();

  // S10: h = silu(e1e@ra10 + b) -> B1
  mfma_gemm<2, 2, 4, 256>(B0, wrow, wcol, wreg + OFF_RA10, lane, acc);
#pragma unroll
  for (int n = 0; n < 2; ++n) {
    float bv = raB[256 + wcol + n * 16 + r15];
#pragma unroll
    for (int m = 0; m < 2; ++m)
#pragma unroll
      for (int r = 0; r < 4; ++r) tmp[m][n][r] = silu_f(acc[m][n][r] + bv);
  }
  __syncthreads();
  write_cd<256>(B1, wrow, wcol, lane, tmp);
  __syncthreads();

  // S11: e1 = e1e + silu(h@ra11 + b) ; optional fused e2
  mfma_gemm<2, 2, 4, 256>(B1, wrow, wcol, wreg + OFF_RA11, lane, acc);
#pragma unroll
  for (int n = 0; n < 2; ++n) {
    int col = wcol + n * 16 + r15;
    float bv = raB[384 + col];
    float wc[6];
#pragma unroll
    for (int q = 0; q < 6; ++q) wc[q] = W_rbf[q * 128 + col];
#pragma unroll
    for (int m = 0; m < 2; ++m)
#pragma unroll
      for (int r = 0; r < 4; ++r) {
        int row = wrow + m * 16 + kg * 4 + r;
        size_t e = e_base + row;
        float val = keep[m][n][r] + silu_f(acc[m][n][r] + bv);
        e1buf[e * 128 + col] = val;
        if (e2o) {
          const float* rp = rbf0 + e * 6;
          float rv = rp[0]*wc[0] + rp[1]*wc[1] + rp[2]*wc[2] + rp[3]*wc[3] + rp[4]*wc[4] + rp[5]*wc[5];
          e2o[e * 128 + col] = val * rv;
        }
      }
  }
}

// ---- fallback C2: e2 = (rbf0 @ W_rbf) * e1 ----
__global__ void __launch_bounds__(256) k_e2(const float* __restrict__ e1,
                                            const float* __restrict__ rbf0,
                                            const float* __restrict__ W_rbf,
                                            float* __restrict__ e2) {
  size_t gid = (size_t)blockIdx.x * 256 + threadIdx.x;
  int e = (int)(gid >> 5);
  int c = (int)(gid & 31) << 2;
  float r6[6];
#pragma unroll
  for (int r = 0; r < 6; ++r) r6[r] = rbf0[(size_t)e * 6 + r];
  float4 v = *(const float4*)(e1 + (size_t)e * 128 + c);
  float4 o;
  float rv;
  rv = 0.f;
#pragma unroll
  for (int r = 0; r < 6; ++r) rv += r6[r] * W_rbf[r * 128 + c + 0];
  o.x = v.x * rv;
  rv = 0.f;
#pragma unroll
  for (int r = 0; r < 6; ++r) rv += r6[r] * W_rbf[r * 128 + c + 1];
  o.y = v.y * rv;
  rv = 0.f;
#pragma unroll
  for (int r = 0; r < 6; ++r) rv += r6[r] * W_rbf[r * 128 + c + 2];
  o.z = v.z * rv;
  rv = 0.f;
#pragma unroll
  for (int r = 0; r < 6; ++r) rv += r6[r] * W_rbf[r * 128 + c + 3];
  o.w = v.w * rv;
  *(float4*)(e2 + (size_t)e * 128 + c) = o;
}

extern "C" void kernel_launch(void* const* d_in, const int* in_sizes, int n_in,
                              void* d_out, int out_size, void* d_ws, size_t ws_size,
                              hipStream_t stream) {
  const float* x1        = (const float*)d_in[0];
  const float* x_old     = (const float*)d_in[1];
  const float* rbf0      = (const float*)d_in[2];
  const float* sbf       = (const float*)d_in[3];
  const int*   idx_kj    = (const int*)d_in[4];
  const int*   idx_ji    = (const int*)d_in[5];
  const float* W_rbf1    = (const float*)d_in[6];
  const float* W_rbf2    = (const float*)d_in[7];
  const float* W_sbf1    = (const float*)d_in[8];
  const float* W_sbf2    = (const float*)d_in[9];
  const float* W_rbf     = (const float*)d_in[10];
  const float* W_kj      = (const float*)d_in[11];
  const float* b_kj      = (const float*)d_in[12];
  const float* W_ji      = (const float*)d_in[13];
  const float* b_ji      = (const float*)d_in[14];
  const float* W_connect = (const float*)d_in[15];
  const float* b_connect = (const float*)d_in[16];
  const float* W_get_up  = (const float*)d_in[17];
  const float* b_get_up  = (const float*)d_in[18];
  const float* W_down    = (const float*)d_in[19];
  const float* b_down    = (const float*)d_in[20];
  const float* W_up      = (const float*)d_in[21];
  const float* b_up      = (const float*)d_in[22];
  const float* rbW       = (const float*)d_in[23];
  const float* rbB       = (const float*)d_in[24];
  const float* W_lin     = (const float*)d_in[25];
  const float* b_lin     = (const float*)d_in[26];
  const float* raW       = (const float*)d_in[27];
  const float* raB       = (const float*)d_in[28];

  float* e1buf = (float*)d_out;                      // sbf_p -> x_up_raw -> e1
  char*  base2 = (char*)d_out + (size_t)E_N * 128 * 4;
  float* e2out = (float*)base2;

  unsigned short* xkj_b = (unsigned short*)(base2 + OFFB_XKJ);
  int* counts = (int*)(base2 + OFFB_CNT);
  int* pos    = (int*)(base2 + OFFB_POS);
  int* tri    = (int*)(base2 + OFFB_TRI);
  int* bsum   = (int*)(base2 + OFFB_BS);
  int* bpre   = (int*)(base2 + OFFB_BP);

  // Fusion of e2 into phaseC1 requires everything phaseC1 READS to live outside
  // the e2 slot (which the fused write covers entirely): wreg + agg -> d_ws.
  const size_t need_ws = (size_t)WREG_BYTES + (size_t)E_N * 64 * 2;
  const bool fuse = ws_size >= need_ws;
  unsigned short* wreg  = fuse ? (unsigned short*)d_ws
                               : (unsigned short*)(base2 + OFFB_WREG);
  unsigned short* agg_b = fuse ? (unsigned short*)((char*)d_ws + WREG_BYTES)
                               : (unsigned short*)(base2 + OFFB_AGG);

  unsigned int* sbfp_u = (unsigned int*)e1buf;   // bf16x2 [T][32] in e1 slot (transient)

  k_prep<<<14, 256, 0, stream>>>(W_kj, W_down, W_up, W_ji, W_get_up, W_connect,
                                 rbW, W_lin, raW, W_rbf1, W_rbf2, wreg);

  // CSR by idx_ji (scan has no buffer aliasing: counts -> pos(local) -> counts/pos)
  hipMemsetAsync(counts, 0, (E_N + 1) * sizeof(int), stream);
  k_hist<<<T_N / 256, 256, 0, stream>>>(idx_ji, counts);
  k_scan1<<<256, 1024, 0, stream>>>(counts, pos, bsum);
  k_scan2<<<1, 256, 0, stream>>>(bsum, bpre, counts);
  k_scan3<<<256, 1024, 0, stream>>>(pos, bpre, counts, pos);
  k_fill<<<T_N / 256, 256, 0, stream>>>(idx_ji, pos, tri);

  // dense sbf_p into e1 slot
  k_sbfp<<<T_N / 8, 256, 0, stream>>>(sbf, W_sbf1, W_sbf2, sbfp_u);

  // x_kj -> down-projected edge features (bf16)
  phaseA<<<E_N / 64, 512, 0, stream>>>(x_old, rbf0, wreg, b_kj, b_down, xkj_b);

  // triplet gather-reduce onto edges (reads sbf_p from e1 slot)
  k_aggB<<<E_N / 8, 256, 0, stream>>>(counts, tri, idx_kj, sbfp_u,
                                      (const unsigned int*)xkj_b, (unsigned int*)agg_b);

  // x1 segment-sum via gather (overwrites e1 slot with x_up_raw)
  k_xupg<<<E_N / 4, 256, 0, stream>>>(counts, tri, x1, e1buf);

  phaseC1<<<E_N / 64, 512, 0, stream>>>(x_old, e1buf, agg_b, wreg,
                                        b_up, b_ji, b_get_up, b_connect, rbB, b_lin, raB,
                                        rbf0, W_rbf, fuse ? e2out : nullptr);
  if (!fuse)
    k_e2<<<E_N * 32 / 256, 256, 0, stream>>>(e1buf, rbf0, W_rbf, e2out);
}